// Round 1
// baseline (535.674 us; speedup 1.0000x reference)
//
#include <hip/hip_runtime.h>
#include <hip/hip_bf16.h>

// Problem constants (from reference): N=64 batch, C=23 chromosomes,
// G=20000 genes, H=64 hidden. x:(N,G,H) f32, chrom_mat:(C,G) one-hot f32,
// attention:(C,H) f32. out:(N,C,H) f32.
#define N_ 64
#define C_ 23
#define G_ 20000
#define H_ 64
#define S_ 4   // slices per (n,c) in the main pass

// ---------------------------------------------------------------------------
// Kernel 1: recover assign[g] = argmax_c chrom_mat[c,g] (one-hot), histogram.
__global__ void assign_kernel(const float* __restrict__ chrom,
                              int* __restrict__ assign,
                              int* __restrict__ counts) {
    int g = blockIdx.x * blockDim.x + threadIdx.x;
    if (g >= G_) return;
    int c_found = 0;
    // uniform 23-iteration scan, no break (cheap, avoids divergence)
    for (int c = 0; c < C_; ++c) {
        if (chrom[c * G_ + g] != 0.f) c_found = c;
    }
    assign[g] = c_found;
    atomicAdd(&counts[c_found], 1);
}

// ---------------------------------------------------------------------------
// Kernel 2: exclusive scan over 23 buckets (serial on one thread — trivial).
__global__ void scan_kernel(const int* __restrict__ counts,
                            int* __restrict__ offsets,
                            int* __restrict__ cursors) {
    if (threadIdx.x == 0 && blockIdx.x == 0) {
        int run = 0;
        for (int c = 0; c < C_; ++c) {
            offsets[c] = run;
            cursors[c] = run;
            run += counts[c];
        }
        offsets[C_] = run;   // == G_
    }
}

// ---------------------------------------------------------------------------
// Kernel 3: counting-sort scatter of gene ids by chromosome.
__global__ void scatter_kernel(const int* __restrict__ assign,
                               int* __restrict__ cursors,
                               int* __restrict__ sorted_g) {
    int g = blockIdx.x * blockDim.x + threadIdx.x;
    if (g >= G_) return;
    int c = assign[g];
    int pos = atomicAdd(&cursors[c], 1);
    sorted_g[pos] = g;
}

// ---------------------------------------------------------------------------
// Kernel 4 (main pass): one block handles (n, c, slice). Chromosome is
// uniform within the block, so attention[c] sits in registers and the
// w*x accumulation stays in registers (zero LDS in the inner loop).
// 16 lanes per gene: float4 load (16B/lane -> one 256B coalesced segment
// per gene), 4-FMA dot partial, 4x shfl_xor reduce within the 16-group.
__global__ __launch_bounds__(256) void main_pass(
    const float* __restrict__ x,        // (N,G,H)
    const float* __restrict__ attn,     // (C,H)
    const int* __restrict__ offsets,    // C+1
    const int* __restrict__ sorted_g,   // G
    float* __restrict__ acc,            // (N,C,H)  zero-initialized
    float* __restrict__ denom)          // (N,C)    zero-initialized
{
    int b = blockIdx.x;
    int s = b % S_; b /= S_;
    int c = b % C_; b /= C_;
    int n = b;

    int beg = offsets[c];
    int end = offsets[c + 1];
    int cnt = end - beg;
    int L   = (cnt + S_ - 1) / S_;
    int lo  = beg + s * L;
    int hi  = min(beg + (s + 1) * L, end);

    int tid = threadIdx.x;
    int sub = tid & 15;   // lane within 16-lane gene group (covers h = 4*sub..4*sub+3)
    int grp = tid >> 4;   // gene group id within block, 0..15

    const float4 a4 = ((const float4*)(attn + c * H_))[sub];

    float4 accv = make_float4(0.f, 0.f, 0.f, 0.f);
    float dsum = 0.f;

    for (int p = lo + grp; p < hi; p += 16) {
        int g = sorted_g[p];
        const float4 x4 = ((const float4*)(x + ((size_t)n * G_ + g) * H_))[sub];
        float part = a4.x * x4.x + a4.y * x4.y + a4.z * x4.z + a4.w * x4.w;
        // reduce dot over the 16 lanes of this gene group
        part += __shfl_xor(part, 1);
        part += __shfl_xor(part, 2);
        part += __shfl_xor(part, 4);
        part += __shfl_xor(part, 8);
        // mask = (att != 0); att == s here since chrom one-hot value is 1.0
        float w;
        if (part == 0.f) {
            w = 0.f;
        } else {
            float lr = (part >= 0.f) ? part : 0.2f * part;
            w = __expf(lr);
        }
        accv.x += w * x4.x;
        accv.y += w * x4.y;
        accv.z += w * x4.z;
        accv.w += w * x4.w;
        dsum += w;   // identical across the 16 lanes of this group
    }

    // Reduce across the 4 gene-groups within the wave (xor lane bits 4,5).
    #pragma unroll
    for (int m = 16; m <= 32; m <<= 1) {
        accv.x += __shfl_xor(accv.x, m);
        accv.y += __shfl_xor(accv.y, m);
        accv.z += __shfl_xor(accv.z, m);
        accv.w += __shfl_xor(accv.w, m);
        dsum   += __shfl_xor(dsum, m);
    }

    // One wave-partial per (block-wave): atomics into global accumulator.
    int lane = tid & 63;
    float* accp = acc + ((size_t)n * C_ + c) * H_;
    if (lane < 16) {
        atomicAdd(accp + sub * 4 + 0, accv.x);
        atomicAdd(accp + sub * 4 + 1, accv.y);
        atomicAdd(accp + sub * 4 + 2, accv.z);
        atomicAdd(accp + sub * 4 + 3, accv.w);
        if (sub == 0) atomicAdd(denom + n * C_ + c, dsum);
    }
}

// ---------------------------------------------------------------------------
// Kernel 5: out = acc / max(denom, 1e-10)
__global__ void finalize_kernel(const float* __restrict__ acc,
                                const float* __restrict__ denom,
                                float* __restrict__ out) {
    int i = blockIdx.x * blockDim.x + threadIdx.x;
    if (i >= N_ * C_ * H_) return;
    int nc = i >> 6;  // / H_
    float d = fmaxf(denom[nc], 1e-10f);
    out[i] = acc[i] / d;
}

// ---------------------------------------------------------------------------
extern "C" void kernel_launch(void* const* d_in, const int* in_sizes, int n_in,
                              void* d_out, int out_size, void* d_ws, size_t ws_size,
                              hipStream_t stream) {
    const float* x     = (const float*)d_in[0];   // N*G*H
    const float* chrom = (const float*)d_in[1];   // C*G
    const float* attn  = (const float*)d_in[2];   // C*H
    float* out = (float*)d_out;

    // Workspace layout (zeroed region first, contiguous):
    //   acc    : N*C*H floats
    //   denom  : N*C   floats
    //   counts : C     ints
    //   cursors: C     ints
    //   offsets: C+1   ints   (fully overwritten by scan_kernel)
    //   assign : G     ints   (fully overwritten)
    //   sorted : G     ints   (fully overwritten)
    float* acc    = (float*)d_ws;
    float* denom  = acc + (size_t)N_ * C_ * H_;
    int*   counts  = (int*)(denom + (size_t)N_ * C_);
    int*   cursors = counts + C_;
    int*   offsets = cursors + C_;
    int*   assign  = offsets + (C_ + 1);
    int*   sorted  = assign + G_;

    size_t zero_bytes = ((size_t)N_ * C_ * H_ + (size_t)N_ * C_ + 2 * C_) * sizeof(float);
    hipMemsetAsync(d_ws, 0, zero_bytes, stream);

    int gb = (G_ + 255) / 256;
    assign_kernel<<<gb, 256, 0, stream>>>(chrom, assign, counts);
    scan_kernel<<<1, 64, 0, stream>>>(counts, offsets, cursors);
    scatter_kernel<<<gb, 256, 0, stream>>>(assign, cursors, sorted);

    int main_blocks = N_ * C_ * S_;  // 5888
    main_pass<<<main_blocks, 256, 0, stream>>>(x, attn, offsets, sorted, acc, denom);

    int fin_blocks = (N_ * C_ * H_ + 255) / 256;
    finalize_kernel<<<fin_blocks, 256, 0, stream>>>(acc, denom, out);
}